// Round 7
// 422.802 us; speedup vs baseline: 1.0173x; 1.0173x over previous
//
#include <hip/hip_runtime.h>

#define NN 50000
#define NE 800000
#define NG 64
#define HID 128
#define DOUT 64
#define LN_EPS 1e-5f
#define NBUK 391   // ceil(50000/128) coarse buckets of 128 dst nodes
#define BCAP 3072  // capacity per bucket
#define EPB 2048   // edges per k_bucket block (391 blocks -> full CU spread)

typedef unsigned int uint32;
typedef unsigned short ushort16;
typedef __attribute__((ext_vector_type(8))) short bf16x8;
typedef __attribute__((ext_vector_type(4))) float f32x4;

// ---- bf16 helpers (RNE pack, cheap unpack) ----
__device__ inline ushort16 f2bf(float f) {
  uint32 u = __float_as_uint(f);
  u += 0x7fffu + ((u >> 16) & 1u);
  return (ushort16)(u >> 16);
}
__device__ inline uint32 pack2(float x, float y) {
  return (uint32)f2bf(x) | ((uint32)f2bf(y) << 16);
}
__device__ inline float bflo(uint32 p) { return __uint_as_float(p << 16); }
__device__ inline float bfhi(uint32 p) { return __uint_as_float(p & 0xffff0000u); }

// accumulate 8 bf16 features from a 16B chunk
__device__ inline void acc8(float* a, uint4 p) {
  a[0] += bflo(p.x); a[1] += bfhi(p.x);
  a[2] += bflo(p.y); a[3] += bfhi(p.y);
  a[4] += bflo(p.z); a[5] += bfhi(p.z);
  a[6] += bflo(p.w); a[7] += bfhi(p.w);
}
// accumulate 8 bf16 features + per-edge relu affine term
__device__ inline void accmsg(float* a, uint4 p, float av, float4 w0, float4 w1,
                              float4 b0, float4 b1) {
  a[0] += bflo(p.x) + fmaxf(av * w0.x + b0.x, 0.f);
  a[1] += bfhi(p.x) + fmaxf(av * w0.y + b0.y, 0.f);
  a[2] += bflo(p.y) + fmaxf(av * w0.z + b0.z, 0.f);
  a[3] += bfhi(p.y) + fmaxf(av * w0.w + b0.w, 0.f);
  a[4] += bflo(p.z) + fmaxf(av * w1.x + b1.x, 0.f);
  a[5] += bfhi(p.z) + fmaxf(av * w1.y + b1.y, 0.f);
  a[6] += bflo(p.w) + fmaxf(av * w1.z + b1.z, 0.f);
  a[7] += bfhi(p.w) + fmaxf(av * w1.w + b1.w, 0.f);
}

// ---- combined init: zero pool accumulators + init bucket cursors ----
__global__ __launch_bounds__(256) void k_init(float* __restrict__ Z, int* __restrict__ bcur) {
  int i = blockIdx.x * 256 + threadIdx.x;
  if (i < NG * 64) Z[i] = 0.f;
  if (i < NBUK) bcur[i] = i * BCAP;
}

// ---------------- CSR build: bucket counting sort ----------------
__global__ __launch_bounds__(1024) void k_bucket(const int* __restrict__ src,
                                                 const int* __restrict__ dst,
                                                 const float* __restrict__ ea,
                                                 int* __restrict__ bcur,
                                                 uint2* __restrict__ tmp, int e) {
  __shared__ int hist[NBUK], lbase[NBUK], lcur[NBUK];
  int t = threadIdx.x;
  for (int i = t; i < NBUK; i += 1024) {
    hist[i] = 0;
    lcur[i] = 0;
  }
  __syncthreads();
  int base_e = blockIdx.x * EPB;
  int dstv[EPB / 1024];
#pragma unroll
  for (int k = 0; k < EPB / 1024; k++) {
    int i = base_e + k * 1024 + t;
    int d = (i < e) ? dst[i] : -1;
    dstv[k] = d;
    if (d >= 0) atomicAdd(&hist[d >> 7], 1);
  }
  __syncthreads();
  for (int i = t; i < NBUK; i += 1024) {
    int c = hist[i];
    int b = 0;
    if (c > 0) b = atomicAdd(&bcur[i], c);
    lbase[i] = b;
  }
  __syncthreads();
#pragma unroll
  for (int k = 0; k < EPB / 1024; k++) {
    int i = base_e + k * 1024 + t;
    int d = dstv[k];
    if (d >= 0) {
      int b = d >> 7;
      int r = atomicAdd(&lcur[b], 1);
      int pos = lbase[b] + r;
      if (pos < (b + 1) * BCAP) {
        uint2 rec;
        rec.x = (uint32)(src[i] & 0xffff) | ((uint32)(d & 127) << 16);
        rec.y = __float_as_uint(ea[i]);
        tmp[pos] = rec;
      }
    }
  }
}

__global__ __launch_bounds__(512) void k_bscan(const int* __restrict__ bcur,
                                               int* __restrict__ bbase,
                                               int* __restrict__ rowptr) {
  __shared__ int s[512];
  int t = threadIdx.x;
  int v = 0;
  if (t < NBUK) {
    v = bcur[t] - t * BCAP;
    if (v > BCAP) v = BCAP;
  }
  s[t] = v;
  __syncthreads();
  for (int off = 1; off < 512; off <<= 1) {
    int x = (t >= off) ? s[t - off] : 0;
    __syncthreads();
    s[t] += x;
    __syncthreads();
  }
  if (t < NBUK) bbase[t] = s[t] - v;
  if (t == 511) {
    bbase[NBUK] = s[511];
    rowptr[NN] = s[511];
  }
}

// emits csrc (4B src) + emsg (uint2: src, edge_attr) + rowptr/dis/invc
__global__ __launch_bounds__(256) void k_bsort(const uint2* __restrict__ tmp,
                                               const int* __restrict__ bcur,
                                               const int* __restrict__ bbase,
                                               int* __restrict__ rowptr,
                                               int* __restrict__ csrc,
                                               uint2* __restrict__ emsg,
                                               float* __restrict__ dis,
                                               float* __restrict__ invc) {
  int b = blockIdx.x;
  __shared__ int hist[128], excl[128], cur[128];
  int t = threadIdx.x;
  if (t < 128) {
    hist[t] = 0;
    cur[t] = 0;
  }
  __syncthreads();
  int cnt = bcur[b] - b * BCAP;
  if (cnt > BCAP) cnt = BCAP;
  int tb = b * BCAP;
  int ob = bbase[b];
  for (int i = t; i < cnt; i += 256) {
    uint2 r = tmp[tb + i];
    atomicAdd(&hist[(r.x >> 16) & 127], 1);
  }
  __syncthreads();
  int myDeg = (t < 128) ? hist[t] : 0;
  for (int off = 1; off < 128; off <<= 1) {
    int x = 0;
    if (t < 128 && t >= off) x = hist[t - off];
    __syncthreads();
    if (t < 128) hist[t] += x;
    __syncthreads();
  }
  if (t < 128) {
    excl[t] = hist[t] - myDeg;
    int node = (b << 7) + t;
    if (node < NN) {
      rowptr[node] = ob + excl[t];
      dis[node] = rsqrtf((float)(myDeg + 1));
      invc[node] = (myDeg > 0) ? 1.0f / (float)myDeg : 1.0f;
    }
  }
  __syncthreads();
  for (int i = t; i < cnt; i += 256) {
    uint2 r = tmp[tb + i];
    int o = (r.x >> 16) & 127;
    int p = atomicAdd(&cur[o], 1);
    int pos = ob + excl[o] + p;
    int s = (int)(r.x & 0xffffu);
    csrc[pos] = s;
    emsg[pos] = make_uint2((uint32)s, r.y);
  }
}

// ---------------- GEMM via MFMA: Y[n,FOUT] = dis[row] * (X[n,128] @ W) ------
template <int FOUT, bool IN_BF, bool OUT_BF>
__global__ __launch_bounds__(256) void k_gemm(const void* __restrict__ Xv,
                                              const float* __restrict__ W,
                                              const float* __restrict__ dis,
                                              void* __restrict__ Yv, int n) {
  const int NT = FOUT / 16;  // 16x16 col-tiles per wave
  __shared__ __align__(16) unsigned short Wt[FOUT][136];
  __shared__ __align__(16) unsigned short Xs[64][136];
  int t = threadIdx.x;
  int row0 = blockIdx.x * 64;
  for (int idx = t; idx < 128 * FOUT; idx += 256) {
    int k = idx / FOUT, col = idx % FOUT;
    Wt[col][k] = (unsigned short)f2bf(W[idx]);
  }
  if (IN_BF) {
    const uint32* Xb = (const uint32*)Xv;
    for (int idx = t; idx < 64 * 64; idx += 256) {
      int r = idx >> 6, c = idx & 63;
      uint32 v = (row0 + r < n) ? Xb[(size_t)(row0 + r) * 64 + c] : 0u;
      *(uint32*)&Xs[r][c * 2] = v;
    }
  } else {
    const float* Xf = (const float*)Xv;
    for (int idx = t; idx < 64 * 64; idx += 256) {
      int r = idx >> 6, c = idx & 63;
      float2 v = make_float2(0.f, 0.f);
      if (row0 + r < n) v = ((const float2*)(Xf + (size_t)(row0 + r) * 128))[c];
      *(uint32*)&Xs[r][c * 2] = pack2(v.x, v.y);
    }
  }
  __syncthreads();
  int lane = t & 63, wv = t >> 6;
  int mrow = lane & 15, q = lane >> 4;
  f32x4 acc[NT];
#pragma unroll
  for (int c = 0; c < NT; c++) acc[c] = (f32x4){0.f, 0.f, 0.f, 0.f};
#pragma unroll
  for (int kt = 0; kt < 4; kt++) {
    bf16x8 af = *(const bf16x8*)&Xs[wv * 16 + mrow][kt * 32 + q * 8];
#pragma unroll
    for (int c = 0; c < NT; c++) {
      bf16x8 bfg = *(const bf16x8*)&Wt[c * 16 + mrow][kt * 32 + q * 8];
      acc[c] = __builtin_amdgcn_mfma_f32_16x16x32_bf16(af, bfg, acc[c], 0, 0, 0);
    }
  }
  // D: col = lane&15, row = (lane>>4)*4 + reg
  float ds[4];
#pragma unroll
  for (int r = 0; r < 4; r++) {
    int rg = row0 + wv * 16 + q * 4 + r;
    ds[r] = (rg < n) ? dis[rg] : 0.f;
  }
#pragma unroll
  for (int c = 0; c < NT; c++) {
    int cg = c * 16 + mrow;
#pragma unroll
    for (int r = 0; r < 4; r++) {
      int rg = row0 + wv * 16 + q * 4 + r;
      if (rg < n) {
        float v = acc[c][r] * ds[r];
        if (OUT_BF)
          ((unsigned short*)Yv)[(size_t)rg * FOUT + cg] = (unsigned short)f2bf(v);
        else
          ((float*)Yv)[(size_t)rg * FOUT + cg] = v;
      }
    }
  }
}

// ---- GCN agg, bf16 table (F=128): node per 32 lanes, 16B/lane, 2 edges in parallel
__global__ __launch_bounds__(256) void k_agg_bf(const uint4* __restrict__ XW4,
                                                const float* __restrict__ dis,
                                                const int* __restrict__ rowptr,
                                                const int* __restrict__ csrc,
                                                const float* __restrict__ bias,
                                                uint4* __restrict__ Hb4, int n) {
  int t = threadIdx.x;
  int l = t & 31, lf = l & 15, es = l >> 4;  // 16 lanes/row, 2 edge slots
  int node = blockIdx.x * 8 + (t >> 5);
  if (node >= n) return;
  float dn = dis[node];
  int beg = rowptr[node], end = rowptr[node + 1];
  float a[8];
#pragma unroll
  for (int j = 0; j < 8; j++) a[j] = 0.f;
  int i = beg;
  for (; i + 16 <= end; i += 16) {  // 16 edges per batch (8 per slot)
    int s[8];
    uint4 p[8];
#pragma unroll
    for (int k = 0; k < 8; k++) s[k] = csrc[i + 2 * k + es];
#pragma unroll
    for (int k = 0; k < 8; k++) p[k] = XW4[(size_t)s[k] * 16 + lf];
#pragma unroll
    for (int k = 0; k < 8; k++) acc8(a, p[k]);
  }
  if (i < end) {  // single predicated tail batch (validity uniform within slot)
    uint4 p[8];
#pragma unroll
    for (int k = 0; k < 8; k++) {
      int e = i + 2 * k + es;
      p[k] = make_uint4(0u, 0u, 0u, 0u);
      if (e < end) p[k] = XW4[(size_t)csrc[e] * 16 + lf];
    }
#pragma unroll
    for (int k = 0; k < 8; k++) acc8(a, p[k]);
  }
#pragma unroll
  for (int j = 0; j < 8; j++) a[j] += __shfl_xor(a[j], 16, 64);
  if (es == 0) {
    uint4 ps = XW4[(size_t)node * 16 + lf];
    float4 b0 = ((const float4*)bias)[2 * lf];
    float4 b1 = ((const float4*)bias)[2 * lf + 1];
    float h0 = dn * (a[0] + bflo(ps.x)) + b0.x;
    float h1 = dn * (a[1] + bfhi(ps.x)) + b0.y;
    float h2 = dn * (a[2] + bflo(ps.y)) + b0.z;
    float h3 = dn * (a[3] + bfhi(ps.y)) + b0.w;
    float h4 = dn * (a[4] + bflo(ps.z)) + b1.x;
    float h5 = dn * (a[5] + bfhi(ps.z)) + b1.y;
    float h6 = dn * (a[6] + bflo(ps.w)) + b1.z;
    float h7 = dn * (a[7] + bfhi(ps.w)) + b1.w;
    Hb4[(size_t)node * 16 + lf] =
        make_uint4(pack2(h0, h1), pack2(h2, h3), pack2(h4, h5), pack2(h6, h7));
  }
}

// -- mean-agg msg + ReLU + LN (F=128): 16B/lane, 2 edges in parallel --
__global__ __launch_bounds__(256) void k_msg_bf(const uint4* __restrict__ Hb4,
                                                const float* __restrict__ ew,
                                                const float* __restrict__ eb,
                                                const int* __restrict__ rowptr,
                                                const uint2* __restrict__ emsg,
                                                const float* __restrict__ invc,
                                                const float* __restrict__ lng,
                                                const float* __restrict__ lnb,
                                                uint4* __restrict__ OUT4, int n) {
  int t = threadIdx.x;
  int l = t & 31, lf = l & 15, es = l >> 4;
  int node = blockIdx.x * 8 + (t >> 5);
  if (node >= n) return;
  int beg = rowptr[node], end = rowptr[node + 1];
  float4 w0 = ((const float4*)ew)[2 * lf], w1 = ((const float4*)ew)[2 * lf + 1];
  float4 b0 = ((const float4*)eb)[2 * lf], b1 = ((const float4*)eb)[2 * lf + 1];
  float a[8];
#pragma unroll
  for (int j = 0; j < 8; j++) a[j] = 0.f;
  int i = beg;
  for (; i + 8 <= end; i += 8) {  // 8 edges per batch (4 per slot)
    uint2 m[4];
    uint4 p[4];
#pragma unroll
    for (int k = 0; k < 4; k++) m[k] = emsg[i + 2 * k + es];
#pragma unroll
    for (int k = 0; k < 4; k++) p[k] = Hb4[(size_t)m[k].x * 16 + lf];
#pragma unroll
    for (int k = 0; k < 4; k++) accmsg(a, p[k], __uint_as_float(m[k].y), w0, w1, b0, b1);
  }
  if (i < end) {  // predicated tail batch
    uint2 m[4];
    uint4 p[4];
    int ok[4];
#pragma unroll
    for (int k = 0; k < 4; k++) {
      int e = i + 2 * k + es;
      ok[k] = (e < end);
      m[k] = make_uint2(0u, 0u);
      if (ok[k]) m[k] = emsg[e];
    }
#pragma unroll
    for (int k = 0; k < 4; k++) {
      p[k] = make_uint4(0u, 0u, 0u, 0u);
      if (ok[k]) p[k] = Hb4[(size_t)m[k].x * 16 + lf];
    }
#pragma unroll
    for (int k = 0; k < 4; k++)
      if (ok[k]) accmsg(a, p[k], __uint_as_float(m[k].y), w0, w1, b0, b1);
  }
#pragma unroll
  for (int j = 0; j < 8; j++) a[j] += __shfl_xor(a[j], 16, 64);
  float ic = invc[node];
  float o[8];
  float s1 = 0.f, s2 = 0.f;
#pragma unroll
  for (int j = 0; j < 8; j++) {
    o[j] = fmaxf(a[j] * ic, 0.f);
    s1 += o[j];
    s2 += o[j] * o[j];
  }
#pragma unroll
  for (int off = 8; off; off >>= 1) {
    s1 += __shfl_xor(s1, off, 64);
    s2 += __shfl_xor(s2, off, 64);
  }
  float mu = s1 * (1.f / 128.f);
  float var = s2 * (1.f / 128.f) - mu * mu;
  float r = rsqrtf(var + LN_EPS);
  if (es == 0) {
    float4 g0 = ((const float4*)lng)[2 * lf], g1 = ((const float4*)lng)[2 * lf + 1];
    float4 B0 = ((const float4*)lnb)[2 * lf], B1 = ((const float4*)lnb)[2 * lf + 1];
    float q0 = (o[0] - mu) * r * g0.x + B0.x;
    float q1 = (o[1] - mu) * r * g0.y + B0.y;
    float q2 = (o[2] - mu) * r * g0.z + B0.z;
    float q3 = (o[3] - mu) * r * g0.w + B0.w;
    float q4 = (o[4] - mu) * r * g1.x + B1.x;
    float q5 = (o[5] - mu) * r * g1.y + B1.y;
    float q6 = (o[6] - mu) * r * g1.z + B1.z;
    float q7 = (o[7] - mu) * r * g1.w + B1.w;
    OUT4[(size_t)node * 16 + lf] =
        make_uint4(pack2(q0, q1), pack2(q2, q3), pack2(q4, q5), pack2(q6, q7));
  }
}

// ---- layer-2 GCN agg (F=64): 16B/lane, 4 edges in parallel (8 lanes/row) ----
__global__ __launch_bounds__(256) void k_agg64b(const uint4* __restrict__ XW4,
                                                const float* __restrict__ dis,
                                                const int* __restrict__ rowptr,
                                                const int* __restrict__ csrc,
                                                const float* __restrict__ bias,
                                                uint4* __restrict__ Hb4, int n) {
  int t = threadIdx.x;
  int l = t & 31, lf = l & 7, es = l >> 3;  // 8 lanes/row, 4 edge slots
  int node = blockIdx.x * 8 + (t >> 5);
  if (node >= n) return;
  float dn = dis[node];
  int beg = rowptr[node], end = rowptr[node + 1];
  float a[8];
#pragma unroll
  for (int j = 0; j < 8; j++) a[j] = 0.f;
  int i = beg;
  for (; i + 16 <= end; i += 16) {  // 16 edges per batch (4 per slot)
    int s[4];
    uint4 p[4];
#pragma unroll
    for (int k = 0; k < 4; k++) s[k] = csrc[i + 4 * k + es];
#pragma unroll
    for (int k = 0; k < 4; k++) p[k] = XW4[(size_t)s[k] * 8 + lf];
#pragma unroll
    for (int k = 0; k < 4; k++) acc8(a, p[k]);
  }
  if (i < end) {
    uint4 p[4];
#pragma unroll
    for (int k = 0; k < 4; k++) {
      int e = i + 4 * k + es;
      p[k] = make_uint4(0u, 0u, 0u, 0u);
      if (e < end) p[k] = XW4[(size_t)csrc[e] * 8 + lf];
    }
#pragma unroll
    for (int k = 0; k < 4; k++) acc8(a, p[k]);
  }
#pragma unroll
  for (int j = 0; j < 8; j++) {
    a[j] += __shfl_xor(a[j], 8, 64);
    a[j] += __shfl_xor(a[j], 16, 64);
  }
  if (l < 8) {
    uint4 ps = XW4[(size_t)node * 8 + lf];
    float4 b0 = ((const float4*)bias)[2 * lf];
    float4 b1 = ((const float4*)bias)[2 * lf + 1];
    float h0 = dn * (a[0] + bflo(ps.x)) + b0.x;
    float h1 = dn * (a[1] + bfhi(ps.x)) + b0.y;
    float h2 = dn * (a[2] + bflo(ps.y)) + b0.z;
    float h3 = dn * (a[3] + bfhi(ps.y)) + b0.w;
    float h4 = dn * (a[4] + bflo(ps.z)) + b1.x;
    float h5 = dn * (a[5] + bfhi(ps.z)) + b1.y;
    float h6 = dn * (a[6] + bflo(ps.w)) + b1.z;
    float h7 = dn * (a[7] + bfhi(ps.w)) + b1.w;
    Hb4[(size_t)node * 8 + lf] =
        make_uint4(pack2(h0, h1), pack2(h2, h3), pack2(h4, h5), pack2(h6, h7));
  }
}

// ---- layer-2 msg mean-agg (F=64), bf16 table in, fp32 out: 4 edges in parallel ----
__global__ __launch_bounds__(256) void k_msg64b(const uint4* __restrict__ Hb4,
                                                const float* __restrict__ ew,
                                                const float* __restrict__ eb,
                                                const int* __restrict__ rowptr,
                                                const uint2* __restrict__ emsg,
                                                const float* __restrict__ invc,
                                                float* __restrict__ OUT, int n) {
  int t = threadIdx.x;
  int l = t & 31, lf = l & 7, es = l >> 3;
  int node = blockIdx.x * 8 + (t >> 5);
  if (node >= n) return;
  int beg = rowptr[node], end = rowptr[node + 1];
  float4 w0 = ((const float4*)ew)[2 * lf], w1 = ((const float4*)ew)[2 * lf + 1];
  float4 b0 = ((const float4*)eb)[2 * lf], b1 = ((const float4*)eb)[2 * lf + 1];
  float a[8];
#pragma unroll
  for (int j = 0; j < 8; j++) a[j] = 0.f;
  int i = beg;
  for (; i + 16 <= end; i += 16) {
    uint2 m[4];
    uint4 p[4];
#pragma unroll
    for (int k = 0; k < 4; k++) m[k] = emsg[i + 4 * k + es];
#pragma unroll
    for (int k = 0; k < 4; k++) p[k] = Hb4[(size_t)m[k].x * 8 + lf];
#pragma unroll
    for (int k = 0; k < 4; k++) accmsg(a, p[k], __uint_as_float(m[k].y), w0, w1, b0, b1);
  }
  if (i < end) {
    uint2 m[4];
    uint4 p[4];
    int ok[4];
#pragma unroll
    for (int k = 0; k < 4; k++) {
      int e = i + 4 * k + es;
      ok[k] = (e < end);
      m[k] = make_uint2(0u, 0u);
      if (ok[k]) m[k] = emsg[e];
    }
#pragma unroll
    for (int k = 0; k < 4; k++) {
      p[k] = make_uint4(0u, 0u, 0u, 0u);
      if (ok[k]) p[k] = Hb4[(size_t)m[k].x * 8 + lf];
    }
#pragma unroll
    for (int k = 0; k < 4; k++)
      if (ok[k]) accmsg(a, p[k], __uint_as_float(m[k].y), w0, w1, b0, b1);
  }
#pragma unroll
  for (int j = 0; j < 8; j++) {
    a[j] += __shfl_xor(a[j], 8, 64);
    a[j] += __shfl_xor(a[j], 16, 64);
  }
  if (l < 8) {
    float ic = invc[node];
    float4* dstp = (float4*)(OUT + (size_t)node * 64 + lf * 8);
    dstp[0] = make_float4(a[0] * ic, a[1] * ic, a[2] * ic, a[3] * ic);
    dstp[1] = make_float4(a[4] * ic, a[5] * ic, a[6] * ic, a[7] * ic);
  }
}

// ------- global mean pool ----------
#define POOL_BLOCKS 256
__global__ __launch_bounds__(256) void k_pool_partial(const float* __restrict__ H,
                                                      const int* __restrict__ batch,
                                                      float* __restrict__ Z, int n) {
  int lane = threadIdx.x & 63;
  int wid = blockIdx.x * 4 + (threadIdx.x >> 6);
  const int WAVES = POOL_BLOCKS * 4;
  int per = (n + WAVES - 1) / WAVES;
  int beg = wid * per;
  int end = beg + per;
  if (end > n) end = n;
  if (beg >= end) return;
  int g = batch[beg];
  float acc = 0.f;
  for (int i = beg; i < end; i++) {
    int gi = batch[i];
    if (gi != g) {
      atomicAdd(&Z[g * 64 + lane], acc);
      acc = 0.f;
      g = gi;
    }
    acc += H[(size_t)i * 64 + lane];
  }
  atomicAdd(&Z[g * 64 + lane], acc);
}

__global__ __launch_bounds__(64) void k_pool_div(float* __restrict__ Z,
                                                 const int* __restrict__ batch, int n) {
  int g = blockIdx.x;
  __shared__ int scnt;
  if (threadIdx.x == 0) {
    int lo = 0, hi = n;
    while (lo < hi) { int m = (lo + hi) >> 1; if (batch[m] < g) lo = m + 1; else hi = m; }
    int b0 = lo;
    lo = 0; hi = n;
    while (lo < hi) { int m = (lo + hi) >> 1; if (batch[m] < g + 1) lo = m + 1; else hi = m; }
    scnt = lo - b0;
  }
  __syncthreads();
  float c = (float)scnt;
  if (c < 1.f) c = 1.f;
  Z[g * 64 + threadIdx.x] /= c;
}

extern "C" void kernel_launch(void* const* d_in, const int* in_sizes, int n_in,
                              void* d_out, int out_size, void* d_ws, size_t ws_size,
                              hipStream_t stream) {
  const float* x = (const float*)d_in[0];
  const int* ei = (const int*)d_in[1];
  const float* ea = (const float*)d_in[2];
  const int* batch = (const int*)d_in[3];
  const float* gw0 = (const float*)d_in[4];
  const float* gb0 = (const float*)d_in[5];
  const float* ew0 = (const float*)d_in[6];
  const float* eb0 = (const float*)d_in[7];
  const float* lg0 = (const float*)d_in[8];
  const float* lb0 = (const float*)d_in[9];
  const float* gw1 = (const float*)d_in[10];
  const float* gb1 = (const float*)d_in[11];
  const float* ew1 = (const float*)d_in[12];
  const float* eb1 = (const float*)d_in[13];
  const float* lg1 = (const float*)d_in[14];
  const float* lb1 = (const float*)d_in[15];
  const float* gw2 = (const float*)d_in[16];
  const float* gb2 = (const float*)d_in[17];
  const float* ew2 = (const float*)d_in[18];
  const float* eb2 = (const float*)d_in[19];
  float* out = (float*)d_out;

  const int* src = ei;
  const int* dst = ei + NE;

  char* w = (char*)d_ws;
  size_t off = 0;
  auto alloc = [&](size_t bytes) -> void* {
    void* p = (void*)(w + off);
    off = (off + bytes + 255) & ~(size_t)255;
    return p;
  };
  int* rowptr = (int*)alloc((NN + 1) * sizeof(int));
  int* bcur = (int*)alloc(NBUK * sizeof(int));
  int* bbase = (int*)alloc((NBUK + 1) * sizeof(int));
  int* csrc = (int*)alloc(NE * sizeof(int));
  uint2* emsg = (uint2*)alloc(NE * sizeof(uint2));
  float* dis = (float*)alloc(NN * sizeof(float));
  float* invc = (float*)alloc(NN * sizeof(float));
  uint2* B1b = (uint2*)alloc((size_t)NN * 32 * sizeof(uint2));  // 128 bf16/row
  uint2* B2b = (uint2*)alloc((size_t)NN * 32 * sizeof(uint2));
  uint32* F1b = (uint32*)alloc((size_t)NN * 32 * sizeof(uint32));  // 64 bf16/row
  uint32* F2b = (uint32*)alloc((size_t)NN * 32 * sizeof(uint32));
  uint2* tmp = (uint2*)alloc((size_t)NBUK * BCAP * sizeof(uint2));  // 9.6 MB

  float* Z = out + (size_t)NN * 64;

  // ---- init + CSR build (bucket counting sort) ----
  hipLaunchKernelGGL(k_init, dim3((NG * 64 + 255) / 256), dim3(256), 0, stream, Z, bcur);
  hipLaunchKernelGGL(k_bucket, dim3((NE + EPB - 1) / EPB), dim3(1024), 0, stream, src, dst, ea,
                     bcur, tmp, NE);
  hipLaunchKernelGGL(k_bscan, dim3(1), dim3(512), 0, stream, bcur, bbase, rowptr);
  hipLaunchKernelGGL(k_bsort, dim3(NBUK), dim3(256), 0, stream, tmp, bcur, bbase, rowptr, csrc,
                     emsg, dis, invc);

  dim3 gemm_grid((NN + 63) / 64), tb(256);
  dim3 node_grid((NN + 7) / 8);

  // Layer 0: x(fp32) -> B1b(dis*xw bf16) -> B2b(h bf16) -> B1b(relu+LN bf16)
  hipLaunchKernelGGL((k_gemm<128, false, true>), gemm_grid, tb, 0, stream, x, gw0, dis, B1b, NN);
  hipLaunchKernelGGL(k_agg_bf, node_grid, tb, 0, stream, (const uint4*)B1b, dis, rowptr, csrc,
                     gb0, (uint4*)B2b, NN);
  hipLaunchKernelGGL(k_msg_bf, node_grid, tb, 0, stream, (const uint4*)B2b, ew0, eb0, rowptr,
                     emsg, invc, lg0, lb0, (uint4*)B1b, NN);
  // Layer 1
  hipLaunchKernelGGL((k_gemm<128, true, true>), gemm_grid, tb, 0, stream, B1b, gw1, dis, B2b, NN);
  hipLaunchKernelGGL(k_agg_bf, node_grid, tb, 0, stream, (const uint4*)B2b, dis, rowptr, csrc,
                     gb1, (uint4*)B1b, NN);
  hipLaunchKernelGGL(k_msg_bf, node_grid, tb, 0, stream, (const uint4*)B1b, ew1, eb1, rowptr,
                     emsg, invc, lg1, lb1, (uint4*)B2b, NN);
  // Layer 2: B2b -> F1b(dis*xw bf16) -> F2b(h bf16) -> d_out (fp32)
  hipLaunchKernelGGL((k_gemm<64, true, true>), gemm_grid, tb, 0, stream, B2b, gw2, dis, F1b, NN);
  hipLaunchKernelGGL(k_agg64b, node_grid, tb, 0, stream, (const uint4*)F1b, dis, rowptr, csrc,
                     gb2, (uint4*)F2b, NN);
  hipLaunchKernelGGL(k_msg64b, node_grid, tb, 0, stream, (const uint4*)F2b, ew2, eb2, rowptr,
                     emsg, invc, out, NN);
  // Pool
  hipLaunchKernelGGL(k_pool_partial, dim3(POOL_BLOCKS), tb, 0, stream, out, batch, Z, NN);
  hipLaunchKernelGGL(k_pool_div, dim3(NG), dim3(64), 0, stream, Z, batch, NN);
}